// Round 8
// baseline (115.315 us; speedup 1.0000x reference)
//
#include <hip/hip_runtime.h>
#include <stdint.h>

typedef signed char s8;
typedef int i32x4 __attribute__((ext_vector_type(4)));

#define B_HALF 4096
#define NROWS 8192
#define DCOL 512
#define BM 128
#define TT 64            // 8192/128
#define NTILES 2080      // TT*(TT+1)/2
#define KT 4             // 512 / 128 bytes per K-step
#define QSCALE 32.0f
#define INV_S2 (1.0f / 1024.0f)
#define PREP_BLOCKS (NROWS / 16)   // 512

// ---------- kernel Z: zero the 4 KB accumulator region ----------
__global__ void zero_kernel(uint4* __restrict__ p) {
  p[threadIdx.x] = (uint4){0u, 0u, 0u, 0u};   // 256 * 16 B = 4096 B
}

// ---------- kernel A: quantize + sqq + colsum + global sumsq + last-block bandwidth ----------
__global__ __launch_bounds__(256) void prep_kernel(const float* __restrict__ src,
    const float* __restrict__ tgt, s8* __restrict__ qp,
    float* __restrict__ sqq, float* __restrict__ colsum,
    double* __restrict__ sumsq_acc, unsigned int* __restrict__ counter,
    float* __restrict__ gf_out) {
  __shared__ float cs[4][DCOL];
  __shared__ double redd[4];
  __shared__ int lastFlag;
  int tid = threadIdx.x;
  int lane = tid & 63, wid = tid >> 6;
  float cpart[8] = {0.f,0.f,0.f,0.f,0.f,0.f,0.f,0.f};
  float myssq = 0.f;
  int row0 = blockIdx.x * 16;
#pragma unroll
  for (int r = 0; r < 4; ++r) {
    int row = row0 + r * 4 + wid;
    const float* x = (row < B_HALF) ? (src + (size_t)row * DCOL)
                                    : (tgt + (size_t)(row - B_HALF) * DCOL);
    float4 v0 = *reinterpret_cast<const float4*>(x + lane * 8);
    float4 v1 = *reinterpret_cast<const float4*>(x + lane * 8 + 4);
    float vals[8] = {v0.x, v0.y, v0.z, v0.w, v1.x, v1.y, v1.z, v1.w};
    union { s8 c[8]; uint2 u; } pu;
    int iq = 0;
#pragma unroll
    for (int q = 0; q < 8; ++q) {
      float f = vals[q];
      myssq += f * f;
      cpart[q] += f;
      int k = __float2int_rn(fminf(fmaxf(f * QSCALE, -127.f), 127.f));
      pu.c[q] = (s8)k;
      iq += k * k;
    }
    *reinterpret_cast<uint2*>(qp + (size_t)row * DCOL + lane * 8) = pu.u;
#pragma unroll
    for (int o = 32; o > 0; o >>= 1) iq += __shfl_down(iq, o);
    if (lane == 0) sqq[row] = (float)iq * INV_S2;   // exact: iq < 2^23
  }
  double dssq = (double)myssq;
#pragma unroll
  for (int o = 32; o > 0; o >>= 1) dssq += __shfl_down(dssq, o);
  if (lane == 0) redd[wid] = dssq;
#pragma unroll
  for (int q = 0; q < 8; ++q) cs[wid][lane * 8 + q] = cpart[q];
  __syncthreads();
  int c = tid;
  atomicAdd(&colsum[c],       cs[0][c]       + cs[1][c]       + cs[2][c]       + cs[3][c]);
  atomicAdd(&colsum[c + 256], cs[0][c + 256] + cs[1][c + 256] + cs[2][c + 256] + cs[3][c + 256]);
  if (tid == 0)
    atomicAdd(sumsq_acc, redd[0] + redd[1] + redd[2] + redd[3]);

  // ---- last block computes bandwidth (atomics-only cross-block reads) ----
  asm volatile("s_waitcnt vmcnt(0)" ::: "memory");
  __syncthreads();
  if (tid == 0)
    lastFlag = ((atomicAdd(counter, 1u) % (unsigned)PREP_BLOCKS) == PREP_BLOCKS - 1);
  __syncthreads();
  if (lastFlag) {
    float c0 = atomicAdd(&colsum[tid], 0.f);
    float c1 = atomicAdd(&colsum[tid + 256], 0.f);
    double scs = (double)c0 * c0 + (double)c1 * c1;
#pragma unroll
    for (int o = 32; o > 0; o >>= 1) scs += __shfl_down(scs, o);
    if (lane == 0) redd[wid] = scs;
    __syncthreads();
    if (tid == 0) {
      double C2 = redd[0] + redd[1] + redd[2] + redd[3];
      double S = atomicAdd(sumsq_acc, 0.0);
      double n = (double)NROWS;
      double bwv = (2.0 * n * S - 2.0 * C2) / (n * n - n);
      gf_out[0] = (float)(-1.0 / (16.0 * bwv));
    }
  }
}

// ---------- kernel B: global-direct i8 MFMA Gram (no LDS staging, no K-loop barriers) ----------
__global__ __launch_bounds__(256, 2) void mmd_gemm_kernel(
    const s8* __restrict__ qp, const float* __restrict__ sqq,
    const float* __restrict__ gf_ptr,
    float* __restrict__ slots, unsigned int* __restrict__ counter,
    float* __restrict__ out) {
  __shared__ float sqR[BM], sqC[BM];
  __shared__ float wpart[4];
  __shared__ double redd[4];
  __shared__ int lastFlag;

  // bijective XCD swizzle (2080 % 8 == 0), then linear-index -> triangle (I<=J)
  int bid = blockIdx.x;
  int t6 = (bid & 7) * (NTILES / 8) + (bid >> 3);
  int I = 0, rem = t6;
  while (rem >= TT - I) { rem -= TT - I; ++I; }
  int J = I + rem;
  int rowStart = I * BM, colStart = J * BM;

  int tid = threadIdx.x;
  int lane = tid & 63, wid = tid >> 6;
  int wr = wid >> 1, wc = wid & 1;
  int r15 = lane & 15, kg = lane >> 4;

  // per-lane fragment base pointers: Gram => both operands are row-reads of qp.
  // lane (r15,kg) of m-th A tile reads 16B at row (rowStart+wr*64+m*16+r15), byte kg*16
  const s8* aP[4];
  const s8* bP[4];
#pragma unroll
  for (int m = 0; m < 4; ++m) {
    aP[m] = qp + (size_t)(rowStart + wr * 64 + m * 16 + r15) * DCOL + kg * 16;
    bP[m] = qp + (size_t)(colStart + wc * 64 + m * 16 + r15) * DCOL + kg * 16;
  }

  if (tid < BM) sqR[tid] = sqq[rowStart + tid];
  else          sqC[tid - BM] = sqq[colStart + (tid - BM)];
  float gf = gf_ptr[0];
  __syncthreads();

  i32x4 acc[4][4];
#pragma unroll
  for (int m = 0; m < 4; ++m)
#pragma unroll
    for (int n = 0; n < 4; ++n) acc[m][n] = (i32x4){0, 0, 0, 0};

  // ---- K-loop: barrier-free, compiler-pipelined L2-hit loads + MFMA ----
#pragma unroll
  for (int kt = 0; kt < KT; ++kt) {
    i32x4 a0[4], a1[4], b0[4], b1[4];
#pragma unroll
    for (int m = 0; m < 4; ++m) {
      a0[m] = *reinterpret_cast<const i32x4*>(aP[m] + kt * 128);
      a1[m] = *reinterpret_cast<const i32x4*>(aP[m] + kt * 128 + 64);
    }
#pragma unroll
    for (int n = 0; n < 4; ++n) {
      b0[n] = *reinterpret_cast<const i32x4*>(bP[n] + kt * 128);
      b1[n] = *reinterpret_cast<const i32x4*>(bP[n] + kt * 128 + 64);
    }
#pragma unroll
    for (int m = 0; m < 4; ++m)
#pragma unroll
      for (int n = 0; n < 4; ++n) {
        acc[m][n] = __builtin_amdgcn_mfma_i32_16x16x64_i8(a0[m], b0[n], acc[m][n], 0, 0, 0);
        acc[m][n] = __builtin_amdgcn_mfma_i32_16x16x64_i8(a1[m], b1[n], acc[m][n], 0, 0, 0);
      }
  }

  // ---- fused epilogue: exact-int dot -> l2 -> u + u^2 + u^4 + u^8 + u^16 ----
  float partial = 0.f;
  int rbase = (lane >> 4) * 4;
#pragma unroll
  for (int m = 0; m < 4; ++m) {
    float sr[4];
#pragma unroll
    for (int e = 0; e < 4; ++e) sr[e] = sqR[wr * 64 + m * 16 + rbase + e];
#pragma unroll
    for (int n = 0; n < 4; ++n) {
      float sc = sqC[wc * 64 + n * 16 + r15];
#pragma unroll
      for (int e = 0; e < 4; ++e) {
        float d = (float)acc[m][n][e] * INV_S2;   // exact (|dot| < 2^23)
        float l2v = sr[e] + sc - 2.f * d;
        float u = __expf(gf * l2v);
        float u2 = u * u, u4 = u2 * u2, u8 = u4 * u4, u16v = u8 * u8;
        partial += u + u2 + u4 + u8 + u16v;
      }
    }
  }
  float wsign = ((I == J) ? 1.f : 2.f) *
                (((rowStart < B_HALF) == (colStart < B_HALF)) ? 1.f : -1.f);
  partial *= wsign;
#pragma unroll
  for (int o = 32; o > 0; o >>= 1) partial += __shfl_down(partial, o);
  if (lane == 0) wpart[wid] = partial;
  __syncthreads();

  // ---- fused finalize: coherent slot write (atomicExch), counter, last-block reduce.
  // NO __threadfence (the R4/R5 killer): device-scope atomics are home-L2 coherent.
  if (tid == 0) {
    float bp = wpart[0] + wpart[1] + wpart[2] + wpart[3];
    atomicExch(&slots[bid], bp);
  }
  asm volatile("s_waitcnt vmcnt(0)" ::: "memory");  // slot write globally complete
  __syncthreads();
  if (tid == 0)
    lastFlag = ((atomicAdd(counter, 1u) % (unsigned)NTILES) == NTILES - 1);
  __syncthreads();
  if (lastFlag) {
    double s = 0.0;
    for (int i = tid; i < NTILES; i += 256)
      s += (double)atomicAdd(&slots[i], 0.f);       // atomic-load: coherent
#pragma unroll
    for (int o = 32; o > 0; o >>= 1) s += __shfl_down(s, o);
    if (lane == 0) redd[wid] = s;
    __syncthreads();
    if (tid == 0)
      out[0] = (float)((redd[0] + redd[1] + redd[2] + redd[3]) / (4096.0 * 4096.0));
  }
}

extern "C" void kernel_launch(void* const* d_in, const int* in_sizes, int n_in,
                              void* d_out, int out_size, void* d_ws, size_t ws_size,
                              hipStream_t stream) {
  const float* src = (const float*)d_in[0];
  const float* tgt = (const float*)d_in[1];
  char* ws = (char*)d_ws;

  float*        colsum    = (float*)(ws + 0);        // 512 f32 (zeroed)
  unsigned int* counter   = (unsigned int*)(ws + 2048);
  double*       sumsq_acc = (double*)(ws + 2056);
  float*        gfp       = (float*)(ws + 2064);
  unsigned int* counter2  = (unsigned int*)(ws + 2080);
  float*        sqq       = (float*)(ws + 4096);     // 8192 f32
  float*        slots     = (float*)(ws + 36864);    // 2080 f32
  s8*           qp        = (s8*)(ws + 131072);      // 8192*512 i8 = 4.19 MB

  zero_kernel<<<1, 256, 0, stream>>>((uint4*)ws);    // zero colsum+counters+sumsq+slots hdr

  prep_kernel<<<PREP_BLOCKS, 256, 0, stream>>>(src, tgt, qp, sqq, colsum,
                                               sumsq_acc, counter, gfp);
  mmd_gemm_kernel<<<NTILES, 256, 0, stream>>>(qp, sqq, gfp, slots, counter2,
                                              (float*)d_out);
}